// Round 1
// baseline (721.343 us; speedup 1.0000x reference)
//
#include <hip/hip_runtime.h>
#include <cstddef>

// ---------------------------------------------------------------------------
// NestedTensorBlock (ViT block, DINOv2-style) on MI355X.
// D=1024, H=16, HD=64. Tokens: x1 8x1024 (tok 0..8191), x2 8x512 (tok 8192..12287).
// Pipeline (all bf16 MFMA GEMMs; residuals in f32; corrections scaled by gamma=1e-5
// so bf16 precision is far inside the 0.108 absmax threshold):
//   wT bf16 transposes -> LN1 -> GEMM qkv -> flash attn -> GEMM proj (+x, *gamma1)
//   -> LN2 -> GEMM fc1 (+gelu) -> GEMM fc2 (out += gamma2*...)
// Workspace: 144 MiB (act aliases dead qkv+attn region).
// ---------------------------------------------------------------------------

typedef __bf16 b16x8 __attribute__((ext_vector_type(8)));
typedef float f32x4 __attribute__((ext_vector_type(4)));
typedef unsigned short u16x8 __attribute__((ext_vector_type(8)));
typedef unsigned short u16x4 __attribute__((ext_vector_type(4)));
typedef float f32x4v __attribute__((ext_vector_type(4)));

__device__ __forceinline__ unsigned short f2bf(float f) {
    unsigned int u = __builtin_bit_cast(unsigned int, f);
    return (unsigned short)((u + 0x7fffu + ((u >> 16) & 1u)) >> 16);
}

#define AS1C(p) ((const __attribute__((address_space(1))) void*)(p))
#define AS3(p)  ((__attribute__((address_space(3))) void*)(p))

#if defined(__has_builtin)
#if __has_builtin(__builtin_amdgcn_global_load_lds)
#define HAVE_GLL 1
#endif
#endif

// ---------------------------------------------------------------------------
// Weight transpose + f32->bf16:  in [K][N] f32  ->  out [N][K] bf16
// ---------------------------------------------------------------------------
__global__ __launch_bounds__(256) void wtrans_k(const float* __restrict__ in,
                                                unsigned short* __restrict__ out,
                                                int K, int N) {
    __shared__ float tile[32][33];
    int n0 = blockIdx.x << 5, k0 = blockIdx.y << 5;
    int tx = threadIdx.x & 31;
    int ty = threadIdx.x >> 5;  // 0..7
#pragma unroll
    for (int j = 0; j < 4; ++j)
        tile[ty + j * 8][tx] = in[(size_t)(k0 + ty + j * 8) * N + n0 + tx];
    __syncthreads();
#pragma unroll
    for (int j = 0; j < 4; ++j)
        out[(size_t)(n0 + ty + j * 8) * K + k0 + tx] = f2bf(tile[tx][ty + j * 8]);
}

// ---------------------------------------------------------------------------
// LayerNorm: row in {srcA (row<split) | srcB}, 1024 cols -> bf16 out
// ---------------------------------------------------------------------------
__global__ __launch_bounds__(256) void ln_k(const float* __restrict__ srcA,
                                            const float* __restrict__ srcB, int split,
                                            const float* __restrict__ w,
                                            const float* __restrict__ b,
                                            unsigned short* __restrict__ out) {
    int row = blockIdx.x;
    const float* src = (row < split) ? srcA + (size_t)row * 1024
                                     : srcB + (size_t)(row - split) * 1024;
    int t = threadIdx.x;
    f32x4v v = *(const f32x4v*)(src + t * 4);
    float s = v[0] + v[1] + v[2] + v[3];
    float s2 = v[0] * v[0] + v[1] * v[1] + v[2] * v[2] + v[3] * v[3];
#pragma unroll
    for (int off = 1; off < 64; off <<= 1) {
        s += __shfl_xor(s, off);
        s2 += __shfl_xor(s2, off);
    }
    __shared__ float red[8];
    int wv4 = t >> 6;
    if ((t & 63) == 0) { red[wv4 * 2] = s; red[wv4 * 2 + 1] = s2; }
    __syncthreads();
    s = red[0] + red[2] + red[4] + red[6];
    s2 = red[1] + red[3] + red[5] + red[7];
    float mean = s * (1.0f / 1024.0f);
    float var = s2 * (1.0f / 1024.0f) - mean * mean;
    float rstd = rsqrtf(var + 1e-5f);
    f32x4v wv = *(const f32x4v*)(w + t * 4);
    f32x4v bv = *(const f32x4v*)(b + t * 4);
    u16x4 ov;
#pragma unroll
    for (int j = 0; j < 4; ++j) ov[j] = f2bf((v[j] - mean) * rstd * wv[j] + bv[j]);
    *(u16x4*)(out + (size_t)row * 1024 + t * 4) = ov;
}

// ---------------------------------------------------------------------------
// m97-structure bf16 GEMM: C[M,N] = A[M,K] * BT[N,K]^T (+bias, epilogue EPI)
// 128x128 tile, BK=32, 4 waves in 2x2, each wave 4x4 16x16 frags.
// EPI: 0 = store bf16 (qkv)          1 = out_f32 = x + gamma1*C (proj)
//      2 = store bf16(gelu(C)) (fc1) 3 = out_f32 += gamma2*C (fc2)
// ---------------------------------------------------------------------------
template <int EPI>
__global__ __launch_bounds__(256) void gemm_k(
    const unsigned short* __restrict__ A, const unsigned short* __restrict__ BT,
    const float* __restrict__ bias, const float* __restrict__ scale,
    const float* __restrict__ rx1, const float* __restrict__ rx2,
    float* __restrict__ outf, unsigned short* __restrict__ outb,
    int M, int N, int K) {
    __shared__ char lds[16384];
    int t = threadIdx.x;
    int lane = t & 63, w = t >> 6, lr = lane & 15, lg = lane >> 4;
    int wm = w >> 1, wn = w & 1;
    int nt = N >> 7;
    int m0 = (blockIdx.x / nt) << 7;
    int n0 = (blockIdx.x % nt) << 7;
    f32x4 acc[4][4] = {};
    int ksteps = K >> 5;
    for (int ks = 0; ks < ksteps; ++ks) {
        int k0 = ks << 5;
#if defined(HAVE_GLL)
#pragma unroll
        for (int issue = 0; issue < 2; ++issue) {
            int i = issue * 256 + t;
            const unsigned short* ga = A + (size_t)(m0 + (i >> 2)) * K + k0 + (i & 3) * 8;
            __builtin_amdgcn_global_load_lds(AS1C(ga), AS3(lds + issue * 4096 + w * 1024), 16, 0, 0);
            const unsigned short* gb = BT + (size_t)(n0 + (i >> 2)) * K + k0 + (i & 3) * 8;
            __builtin_amdgcn_global_load_lds(AS1C(gb), AS3(lds + 8192 + issue * 4096 + w * 1024), 16, 0, 0);
        }
#else
#pragma unroll
        for (int issue = 0; issue < 2; ++issue) {
            int i = issue * 256 + t;
            u16x8 ta = *(const u16x8*)(A + (size_t)(m0 + (i >> 2)) * K + k0 + (i & 3) * 8);
            u16x8 tb = *(const u16x8*)(BT + (size_t)(n0 + (i >> 2)) * K + k0 + (i & 3) * 8);
            *(u16x8*)(lds + i * 16) = ta;
            *(u16x8*)(lds + 8192 + i * 16) = tb;
        }
#endif
        __syncthreads();
        b16x8 a[4], b[4];
#pragma unroll
        for (int m = 0; m < 4; ++m)
            a[m] = *(const b16x8*)(lds + ((wm * 64 + m * 16 + lr) * 32 + lg * 8) * 2);
#pragma unroll
        for (int n = 0; n < 4; ++n)
            b[n] = *(const b16x8*)(lds + 8192 + ((wn * 64 + n * 16 + lr) * 32 + lg * 8) * 2);
#pragma unroll
        for (int m = 0; m < 4; ++m)
#pragma unroll
            for (int n = 0; n < 4; ++n)
                acc[m][n] = __builtin_amdgcn_mfma_f32_16x16x32_bf16(a[m], b[n], acc[m][n], 0, 0, 0);
        __syncthreads();
    }
#pragma unroll
    for (int m = 0; m < 4; ++m) {
        int row = m0 + wm * 64 + m * 16 + lg * 4;
#pragma unroll
        for (int n = 0; n < 4; ++n) {
            int col = n0 + wn * 64 + n * 16 + lr;
            float bval = bias[col];
#pragma unroll
            for (int r = 0; r < 4; ++r) {
                float c = acc[m][n][r] + bval;
                size_t idx = (size_t)(row + r) * N + col;
                if (EPI == 0) {
                    outb[idx] = f2bf(c);
                } else if (EPI == 1) {
                    float xv = (row + r < 8192) ? rx1[idx] : rx2[idx - (size_t)8192 * 1024];
                    outf[idx] = xv + scale[col] * c;
                } else if (EPI == 2) {
                    float g = 0.5f * c * (1.0f + erff(c * 0.70710678118654752f));
                    outb[idx] = f2bf(g);
                } else {
                    outf[idx] += scale[col] * c;
                }
            }
        }
    }
}

// ---------------------------------------------------------------------------
// Flash attention: one block = (seq, head, 64-row Q tile). 4 waves x 16 q-rows.
// qkv layout: [token][3072] bf16 with q|k|v, head h at offset h*64 (+0/+1024/+2048).
// ---------------------------------------------------------------------------
__global__ __launch_bounds__(256) void attn_k(const unsigned short* __restrict__ qkv,
                                              unsigned short* __restrict__ aout) {
    __shared__ unsigned short Kl[64 * 72];
    __shared__ unsigned short Vt[64 * 72];     // transposed: [hd][kv]
    __shared__ unsigned short Pl[4][16 * 72];  // per-wave P tile [qrow][kv]
    int bid = blockIdx.x;
    int t = threadIdx.x, lane = t & 63, w = t >> 6, lr = lane & 15, lg = lane >> 4;
    int seq0, S, h, qt;
    if (bid < 2048) {  // x1: 8 seqs * 16 heads * 16 qtiles
        int b = bid >> 8, r = bid & 255;
        h = r >> 4; qt = r & 15; seq0 = b << 10; S = 1024;
    } else {           // x2: 8 seqs * 16 heads * 8 qtiles
        int i2 = bid - 2048;
        int b = i2 >> 7, r = i2 & 127;
        h = r >> 3; qt = r & 7; seq0 = 8192 + (b << 9); S = 512;
    }
    int tok0 = seq0 + qt * 64;
    const size_t hoff = (size_t)h * 64;
    b16x8 aq0, aq1;
    {
        const unsigned short* qb = qkv + (size_t)(tok0 + w * 16 + lr) * 3072 + hoff;
        aq0 = *(const b16x8*)(qb + lg * 8);
        aq1 = *(const b16x8*)(qb + 32 + lg * 8);
    }
    float m_run[4] = {-1e30f, -1e30f, -1e30f, -1e30f};
    float l_run[4] = {0.f, 0.f, 0.f, 0.f};
    f32x4 o[4] = {};
    int nkv = S >> 6;
    for (int kt = 0; kt < nkv; ++kt) {
        int kv0 = seq0 + (kt << 6);
#pragma unroll
        for (int issue = 0; issue < 2; ++issue) {
            int i = issue * 256 + t;
            {   // K tile: [kv][hd], padded stride 72
                int row = i >> 3, c = (i & 7) << 3;
                u16x8 tmp = *(const u16x8*)(qkv + (size_t)(kv0 + row) * 3072 + 1024 + hoff + c);
                *(u16x8*)(&Kl[row * 72 + c]) = tmp;
            }
            {   // V tile transposed: wave-contiguous kv columns -> conflict-free 2B writes
                int kvr = i & 63, cg = ((i >> 6) & 7) << 3;
                u16x8 tmp = *(const u16x8*)(qkv + (size_t)(kv0 + kvr) * 3072 + 2048 + hoff + cg);
#pragma unroll
                for (int j = 0; j < 8; ++j) Vt[(cg + j) * 72 + kvr] = tmp[j];
            }
        }
        __syncthreads();
        f32x4 s[4];
#pragma unroll
        for (int n = 0; n < 4; ++n) {
            b16x8 bk0 = *(const b16x8*)(&Kl[(n * 16 + lr) * 72 + lg * 8]);
            b16x8 bk1 = *(const b16x8*)(&Kl[(n * 16 + lr) * 72 + 32 + lg * 8]);
            f32x4 z = {};
            z = __builtin_amdgcn_mfma_f32_16x16x32_bf16(aq0, bk0, z, 0, 0, 0);
            z = __builtin_amdgcn_mfma_f32_16x16x32_bf16(aq1, bk1, z, 0, 0, 0);
            s[n] = z;
        }
#pragma unroll
        for (int n = 0; n < 4; ++n) s[n] *= 0.125f;  // 1/sqrt(64)
        float p[4][4];
#pragma unroll
        for (int r = 0; r < 4; ++r) {
            float tm = fmaxf(fmaxf(s[0][r], s[1][r]), fmaxf(s[2][r], s[3][r]));
            tm = fmaxf(tm, __shfl_xor(tm, 1));
            tm = fmaxf(tm, __shfl_xor(tm, 2));
            tm = fmaxf(tm, __shfl_xor(tm, 4));
            tm = fmaxf(tm, __shfl_xor(tm, 8));
            float mn = fmaxf(m_run[r], tm);
            float alpha = __expf(m_run[r] - mn);
            m_run[r] = mn;
            float rs = 0.f;
#pragma unroll
            for (int n = 0; n < 4; ++n) {
                float pv = __expf(s[n][r] - mn);
                p[n][r] = pv;
                rs += pv;
            }
            rs += __shfl_xor(rs, 1);
            rs += __shfl_xor(rs, 2);
            rs += __shfl_xor(rs, 4);
            rs += __shfl_xor(rs, 8);
            l_run[r] = l_run[r] * alpha + rs;
#pragma unroll
            for (int n = 0; n < 4; ++n) o[n][r] *= alpha;
        }
#pragma unroll
        for (int r = 0; r < 4; ++r)
#pragma unroll
            for (int n = 0; n < 4; ++n)
                Pl[w][(lg * 4 + r) * 72 + n * 16 + lr] = f2bf(p[n][r]);
        __syncthreads();  // Pl visible (and keeps waves in lockstep)
        b16x8 ap0 = *(const b16x8*)(&Pl[w][lr * 72 + lg * 8]);
        b16x8 ap1 = *(const b16x8*)(&Pl[w][lr * 72 + 32 + lg * 8]);
#pragma unroll
        for (int n = 0; n < 4; ++n) {
            b16x8 bv0 = *(const b16x8*)(&Vt[(n * 16 + lr) * 72 + lg * 8]);
            b16x8 bv1 = *(const b16x8*)(&Vt[(n * 16 + lr) * 72 + 32 + lg * 8]);
            o[n] = __builtin_amdgcn_mfma_f32_16x16x32_bf16(ap0, bv0, o[n], 0, 0, 0);
            o[n] = __builtin_amdgcn_mfma_f32_16x16x32_bf16(ap1, bv1, o[n], 0, 0, 0);
        }
        __syncthreads();  // protect Kl/Vt before next stage
    }
#pragma unroll
    for (int r = 0; r < 4; ++r) {
        float inv = 1.0f / l_run[r];
#pragma unroll
        for (int n = 0; n < 4; ++n)
            aout[(size_t)(tok0 + w * 16 + lg * 4 + r) * 1024 + hoff + n * 16 + lr] =
                f2bf(o[n][r] * inv);
    }
}

// ---------------------------------------------------------------------------
// Launch
// ---------------------------------------------------------------------------
extern "C" void kernel_launch(void* const* d_in, const int* in_sizes, int n_in,
                              void* d_out, int out_size, void* d_ws, size_t ws_size,
                              hipStream_t stream) {
    const float* x1     = (const float*)d_in[0];
    const float* x2     = (const float*)d_in[1];
    const float* w_qkv  = (const float*)d_in[2];
    const float* b_qkv  = (const float*)d_in[3];
    const float* w_proj = (const float*)d_in[4];
    const float* b_proj = (const float*)d_in[5];
    const float* ln1w   = (const float*)d_in[6];
    const float* ln1b   = (const float*)d_in[7];
    const float* ln2w   = (const float*)d_in[8];
    const float* ln2b   = (const float*)d_in[9];
    const float* w_fc1  = (const float*)d_in[10];
    const float* b_fc1  = (const float*)d_in[11];
    const float* w_fc2  = (const float*)d_in[12];
    const float* b_fc2  = (const float*)d_in[13];
    const float* gamma1 = (const float*)d_in[14];
    const float* gamma2 = (const float*)d_in[15];
    float* out = (float*)d_out;
    char* ws = (char*)d_ws;

    // Workspace layout (144 MiB total; all offsets 256B-aligned)
    unsigned short* wqkvT  = (unsigned short*)(ws);              //  6291456 B
    unsigned short* wprojT = (unsigned short*)(ws + 6291456);    //  2097152 B
    unsigned short* wfc1T  = (unsigned short*)(ws + 8388608);    //  8388608 B
    unsigned short* wfc2T  = (unsigned short*)(ws + 16777216);   //  8388608 B
    unsigned short* lnbuf  = (unsigned short*)(ws + 25165824);   // 25165824 B
    unsigned short* qkvbuf = (unsigned short*)(ws + 50331648);   // 75497472 B
    unsigned short* attnbuf= (unsigned short*)(ws + 125829120);  // 25165824 B
    unsigned short* actbuf = (unsigned short*)(ws + 50331648);   // aliases qkv+attn (both dead by then)

    // 1) weights -> bf16, transposed to [N][K]
    wtrans_k<<<dim3(96, 32), 256, 0, stream>>>(w_qkv, wqkvT, 1024, 3072);
    wtrans_k<<<dim3(32, 32), 256, 0, stream>>>(w_proj, wprojT, 1024, 1024);
    wtrans_k<<<dim3(128, 32), 256, 0, stream>>>(w_fc1, wfc1T, 1024, 4096);
    wtrans_k<<<dim3(32, 128), 256, 0, stream>>>(w_fc2, wfc2T, 4096, 1024);
    // 2) LN1 over packed tokens
    ln_k<<<12288, 256, 0, stream>>>(x1, x2, 8192, ln1w, ln1b, lnbuf);
    // 3) qkv = LN1(x) @ w_qkv + b_qkv          [12288,3072] bf16
    gemm_k<0><<<96 * 24, 256, 0, stream>>>(lnbuf, wqkvT, b_qkv, nullptr, nullptr, nullptr,
                                           nullptr, qkvbuf, 12288, 3072, 1024);
    // 4) flash attention -> attnbuf [12288,1024] bf16
    attn_k<<<3072, 256, 0, stream>>>(qkvbuf, attnbuf);
    // 5) y = x + gamma1*(attn @ w_proj + b_proj)  -> d_out f32
    gemm_k<1><<<96 * 8, 256, 0, stream>>>(attnbuf, wprojT, b_proj, gamma1, x1, x2,
                                          out, nullptr, 12288, 1024, 1024);
    // 6) LN2 over y
    ln_k<<<12288, 256, 0, stream>>>(out, out + (size_t)8192 * 1024, 8192, ln2w, ln2b, lnbuf);
    // 7) act = gelu(LN2 @ w_fc1 + b_fc1)        [12288,4096] bf16
    gemm_k<2><<<96 * 32, 256, 0, stream>>>(lnbuf, wfc1T, b_fc1, nullptr, nullptr, nullptr,
                                           nullptr, actbuf, 12288, 4096, 1024);
    // 8) out += gamma2*(act @ w_fc2 + b_fc2)
    gemm_k<3><<<96 * 8, 256, 0, stream>>>(actbuf, wfc2T, b_fc2, gamma2, nullptr, nullptr,
                                          out, nullptr, 12288, 1024, 4096);
}

// Round 2
// 689.314 us; speedup vs baseline: 1.0465x; 1.0465x over previous
//
#include <hip/hip_runtime.h>
#include <cstddef>

// ---------------------------------------------------------------------------
// NestedTensorBlock (ViT block) on MI355X.
// D=1024, H=16, HD=64. Tokens: x1 8x1024 (tok 0..8191), x2 8x512 (tok 8192..12287).
// GEMMs: 256x256-tile, 8-wave, BK=32, 4-slot LDS ring, depth-3 prefetch with
// counted vmcnt (never 0 in main loop), setprio around MFMA cluster.
// ---------------------------------------------------------------------------

typedef __bf16 b16x8 __attribute__((ext_vector_type(8)));
typedef float f32x4 __attribute__((ext_vector_type(4)));
typedef unsigned short u16x8 __attribute__((ext_vector_type(8)));
typedef unsigned short u16x4 __attribute__((ext_vector_type(4)));
typedef float f32x4v __attribute__((ext_vector_type(4)));

__device__ __forceinline__ unsigned short f2bf(float f) {
    unsigned int u = __builtin_bit_cast(unsigned int, f);
    return (unsigned short)((u + 0x7fffu + ((u >> 16) & 1u)) >> 16);
}

#define AS1C(p) ((const __attribute__((address_space(1))) void*)(p))
#define AS3(p)  ((__attribute__((address_space(3))) void*)(p))
#define FENCE() asm volatile("" ::: "memory")

// ---------------------------------------------------------------------------
// Weight transpose + f32->bf16:  in [K][N] f32  ->  out [N][K] bf16
// ---------------------------------------------------------------------------
__global__ __launch_bounds__(256) void wtrans_k(const float* __restrict__ in,
                                                unsigned short* __restrict__ out,
                                                int K, int N) {
    __shared__ float tile[32][33];
    int n0 = blockIdx.x << 5, k0 = blockIdx.y << 5;
    int tx = threadIdx.x & 31;
    int ty = threadIdx.x >> 5;  // 0..7
#pragma unroll
    for (int j = 0; j < 4; ++j)
        tile[ty + j * 8][tx] = in[(size_t)(k0 + ty + j * 8) * N + n0 + tx];
    __syncthreads();
#pragma unroll
    for (int j = 0; j < 4; ++j)
        out[(size_t)(n0 + ty + j * 8) * K + k0 + tx] = f2bf(tile[tx][ty + j * 8]);
}

// ---------------------------------------------------------------------------
// LayerNorm: row in {srcA (row<split) | srcB}, 1024 cols -> bf16 out
// ---------------------------------------------------------------------------
__global__ __launch_bounds__(256) void ln_k(const float* __restrict__ srcA,
                                            const float* __restrict__ srcB, int split,
                                            const float* __restrict__ w,
                                            const float* __restrict__ b,
                                            unsigned short* __restrict__ out) {
    int row = blockIdx.x;
    const float* src = (row < split) ? srcA + (size_t)row * 1024
                                     : srcB + (size_t)(row - split) * 1024;
    int t = threadIdx.x;
    f32x4v v = *(const f32x4v*)(src + t * 4);
    float s = v[0] + v[1] + v[2] + v[3];
    float s2 = v[0] * v[0] + v[1] * v[1] + v[2] * v[2] + v[3] * v[3];
#pragma unroll
    for (int off = 1; off < 64; off <<= 1) {
        s += __shfl_xor(s, off);
        s2 += __shfl_xor(s2, off);
    }
    __shared__ float red[8];
    int wv4 = t >> 6;
    if ((t & 63) == 0) { red[wv4 * 2] = s; red[wv4 * 2 + 1] = s2; }
    __syncthreads();
    s = red[0] + red[2] + red[4] + red[6];
    s2 = red[1] + red[3] + red[5] + red[7];
    float mean = s * (1.0f / 1024.0f);
    float var = s2 * (1.0f / 1024.0f) - mean * mean;
    float rstd = rsqrtf(var + 1e-5f);
    f32x4v wv = *(const f32x4v*)(w + t * 4);
    f32x4v bv = *(const f32x4v*)(b + t * 4);
    u16x4 ov;
#pragma unroll
    for (int j = 0; j < 4; ++j) ov[j] = f2bf((v[j] - mean) * rstd * wv[j] + bv[j]);
    *(u16x4*)(out + (size_t)row * 1024 + t * 4) = ov;
}

// ---------------------------------------------------------------------------
// 256x256-tile bf16 GEMM: C[M,NN] = A[M,K] * BT[NN,K]^T (+bias, epilogue EPI)
// 512 threads = 8 waves in 2(M)x4(N); per-wave output 128x64 = 8x4 16x16 frags.
// BK=32; LDS = 4 ring slots x (A 16KB + B 16KB) = 128 KiB; stage(t+3) while
// computing t; vmcnt(12) (= 3 tiles x 4 loads in flight) before consuming.
// EPI: 0 = store bf16 (qkv)          1 = out_f32 = x + gamma1*C (proj)
//      2 = store bf16(gelu(C)) (fc1) 3 = out_f32 += gamma2*C (fc2)
// ---------------------------------------------------------------------------
template <int K, int NN, int EPI>
__global__ __launch_bounds__(512, 2) void gemm2_k(
    const unsigned short* __restrict__ A, const unsigned short* __restrict__ BT,
    const float* __restrict__ bias, const float* __restrict__ scale,
    const float* __restrict__ rx1, const float* __restrict__ rx2,
    float* __restrict__ outf, unsigned short* __restrict__ outb) {
    __shared__ char lds[131072];
    constexpr int NT = K / 32;
    constexpr int ntn = NN >> 8;
    const int t = threadIdx.x;
    const int lane = t & 63, w = t >> 6, lr = lane & 15, lg = lane >> 4;
    const int wm = w >> 2, wn = w & 3;
    // bijective XCD swizzle (all grids are multiples of 8)
    const int nwg = gridDim.x;
    const int bid = blockIdx.x;
    const int swz = (bid & 7) * (nwg >> 3) + (bid >> 3);
    const int m0 = (swz / ntn) << 8;
    const int n0 = (swz % ntn) << 8;

    // per-thread global staging bases (issue i covers LDS chunk i*512 + t)
    const unsigned short* gA0 = A + (size_t)(m0 + (t >> 2)) * K + (t & 3) * 8;
    const unsigned short* gA1 = gA0 + (size_t)128 * K;
    const unsigned short* gB0 = BT + (size_t)(n0 + (t >> 2)) * K + (t & 3) * 8;
    const unsigned short* gB1 = gB0 + (size_t)128 * K;
    const int wbase = w * 1024;  // wave-uniform LDS offset within each 8KB issue region

    f32x4 acc[8][4] = {};

    auto STAGE = [&](int kt) {
        char* sb = lds + (kt & 3) * 32768;
        int ko = kt * 32;
        __builtin_amdgcn_global_load_lds(AS1C(gA0 + ko), AS3(sb + wbase), 16, 0, 0);
        __builtin_amdgcn_global_load_lds(AS1C(gA1 + ko), AS3(sb + 8192 + wbase), 16, 0, 0);
        __builtin_amdgcn_global_load_lds(AS1C(gB0 + ko), AS3(sb + 16384 + wbase), 16, 0, 0);
        __builtin_amdgcn_global_load_lds(AS1C(gB1 + ko), AS3(sb + 24576 + wbase), 16, 0, 0);
    };
    auto COMPUTE = [&](int kt) {
        const char* sa = lds + (kt & 3) * 32768 + (wm * 128 + lr) * 64 + lg * 16;
        const char* sq = lds + (kt & 3) * 32768 + 16384 + (wn * 64 + lr) * 64 + lg * 16;
        b16x8 af[8], bf[4];
#pragma unroll
        for (int m = 0; m < 8; ++m) af[m] = *(const b16x8*)(sa + m * 1024);
#pragma unroll
        for (int n = 0; n < 4; ++n) bf[n] = *(const b16x8*)(sq + n * 1024);
        __builtin_amdgcn_s_setprio(1);
#pragma unroll
        for (int m = 0; m < 8; ++m)
#pragma unroll
            for (int n = 0; n < 4; ++n)
                acc[m][n] = __builtin_amdgcn_mfma_f32_16x16x32_bf16(af[m], bf[n], acc[m][n], 0, 0, 0);
        __builtin_amdgcn_s_setprio(0);
    };

    STAGE(0); STAGE(1); STAGE(2);
    for (int kt = 0; kt < NT - 3; ++kt) {
        STAGE(kt + 3);
        asm volatile("s_waitcnt vmcnt(12)" ::: "memory");  // stage(kt) landed (this wave)
        __builtin_amdgcn_s_barrier();                      // ...and all waves
        FENCE();
        COMPUTE(kt);
        FENCE();
        __builtin_amdgcn_s_barrier();                      // slot kt free for overwrite
        FENCE();
    }
    asm volatile("s_waitcnt vmcnt(8)" ::: "memory");
    __builtin_amdgcn_s_barrier(); FENCE();
    COMPUTE(NT - 3); FENCE();
    __builtin_amdgcn_s_barrier(); FENCE();
    asm volatile("s_waitcnt vmcnt(4)" ::: "memory");
    __builtin_amdgcn_s_barrier(); FENCE();
    COMPUTE(NT - 2); FENCE();
    __builtin_amdgcn_s_barrier(); FENCE();
    asm volatile("s_waitcnt vmcnt(0)" ::: "memory");
    __builtin_amdgcn_s_barrier(); FENCE();
    COMPUTE(NT - 1);

    // epilogue
    const int rbase = m0 + wm * 128 + lg * 4;
    const int cbase = n0 + wn * 64 + lr;
#pragma unroll
    for (int n = 0; n < 4; ++n) {
        int col = cbase + n * 16;
        float bval = bias[col];
        float sval = (EPI == 1 || EPI == 3) ? scale[col] : 0.f;
#pragma unroll
        for (int m = 0; m < 8; ++m) {
            int row = rbase + m * 16;
#pragma unroll
            for (int r = 0; r < 4; ++r) {
                float c = acc[m][n][r] + bval;
                size_t idx = (size_t)(row + r) * NN + col;
                if (EPI == 0) {
                    outb[idx] = f2bf(c);
                } else if (EPI == 1) {
                    float xv = (row + r < 8192) ? rx1[idx] : rx2[idx - (size_t)8192 * 1024];
                    outf[idx] = xv + sval * c;
                } else if (EPI == 2) {
                    // gelu(c) = c * sigmoid(2*0.7978845608*(c + 0.044715 c^3))
                    float u = c * (c * c * 0.044715f + 1.0f) * 1.5957691216057308f;
                    outb[idx] = f2bf(c / (1.0f + __expf(-u)));
                } else {
                    outf[idx] += sval * c;
                }
            }
        }
    }
}

// ---------------------------------------------------------------------------
// Flash attention: one block = (seq, head, 64-row Q tile). 4 waves x 16 q-rows.
// qkv layout: [token][3072] bf16 with q|k|v, head h at offset h*64 (+0/+1024/+2048).
// ---------------------------------------------------------------------------
__global__ __launch_bounds__(256) void attn_k(const unsigned short* __restrict__ qkv,
                                              unsigned short* __restrict__ aout) {
    __shared__ unsigned short Kl[64 * 72];
    __shared__ unsigned short Vt[64 * 72];     // transposed: [hd][kv]
    __shared__ unsigned short Pl[4][16 * 72];  // per-wave P tile [qrow][kv]
    int bid = blockIdx.x;
    int t = threadIdx.x, lane = t & 63, w = t >> 6, lr = lane & 15, lg = lane >> 4;
    int seq0, S, h, qt;
    if (bid < 2048) {  // x1: 8 seqs * 16 heads * 16 qtiles
        int b = bid >> 8, r = bid & 255;
        h = r >> 4; qt = r & 15; seq0 = b << 10; S = 1024;
    } else {           // x2: 8 seqs * 16 heads * 8 qtiles
        int i2 = bid - 2048;
        int b = i2 >> 7, r = i2 & 127;
        h = r >> 3; qt = r & 7; seq0 = 8192 + (b << 9); S = 512;
    }
    int tok0 = seq0 + qt * 64;
    const size_t hoff = (size_t)h * 64;
    b16x8 aq0, aq1;
    {
        const unsigned short* qb = qkv + (size_t)(tok0 + w * 16 + lr) * 3072 + hoff;
        aq0 = *(const b16x8*)(qb + lg * 8);
        aq1 = *(const b16x8*)(qb + 32 + lg * 8);
    }
    float m_run[4] = {-1e30f, -1e30f, -1e30f, -1e30f};
    float l_run[4] = {0.f, 0.f, 0.f, 0.f};
    f32x4 o[4] = {};
    int nkv = S >> 6;
    for (int kt = 0; kt < nkv; ++kt) {
        int kv0 = seq0 + (kt << 6);
#pragma unroll
        for (int issue = 0; issue < 2; ++issue) {
            int i = issue * 256 + t;
            {   // K tile: [kv][hd], padded stride 72
                int row = i >> 3, c = (i & 7) << 3;
                u16x8 tmp = *(const u16x8*)(qkv + (size_t)(kv0 + row) * 3072 + 1024 + hoff + c);
                *(u16x8*)(&Kl[row * 72 + c]) = tmp;
            }
            {   // V tile transposed
                int kvr = i & 63, cg = ((i >> 6) & 7) << 3;
                u16x8 tmp = *(const u16x8*)(qkv + (size_t)(kv0 + kvr) * 3072 + 2048 + hoff + cg);
#pragma unroll
                for (int j = 0; j < 8; ++j) Vt[(cg + j) * 72 + kvr] = tmp[j];
            }
        }
        __syncthreads();
        f32x4 s[4];
#pragma unroll
        for (int n = 0; n < 4; ++n) {
            b16x8 bk0 = *(const b16x8*)(&Kl[(n * 16 + lr) * 72 + lg * 8]);
            b16x8 bk1 = *(const b16x8*)(&Kl[(n * 16 + lr) * 72 + 32 + lg * 8]);
            f32x4 z = {};
            z = __builtin_amdgcn_mfma_f32_16x16x32_bf16(aq0, bk0, z, 0, 0, 0);
            z = __builtin_amdgcn_mfma_f32_16x16x32_bf16(aq1, bk1, z, 0, 0, 0);
            s[n] = z;
        }
#pragma unroll
        for (int n = 0; n < 4; ++n) s[n] *= 0.125f;  // 1/sqrt(64)
        float p[4][4];
#pragma unroll
        for (int r = 0; r < 4; ++r) {
            float tm = fmaxf(fmaxf(s[0][r], s[1][r]), fmaxf(s[2][r], s[3][r]));
            tm = fmaxf(tm, __shfl_xor(tm, 1));
            tm = fmaxf(tm, __shfl_xor(tm, 2));
            tm = fmaxf(tm, __shfl_xor(tm, 4));
            tm = fmaxf(tm, __shfl_xor(tm, 8));
            float mn = fmaxf(m_run[r], tm);
            float alpha = __expf(m_run[r] - mn);
            m_run[r] = mn;
            float rs = 0.f;
#pragma unroll
            for (int n = 0; n < 4; ++n) {
                float pv = __expf(s[n][r] - mn);
                p[n][r] = pv;
                rs += pv;
            }
            rs += __shfl_xor(rs, 1);
            rs += __shfl_xor(rs, 2);
            rs += __shfl_xor(rs, 4);
            rs += __shfl_xor(rs, 8);
            l_run[r] = l_run[r] * alpha + rs;
#pragma unroll
            for (int n = 0; n < 4; ++n) o[n][r] *= alpha;
        }
#pragma unroll
        for (int r = 0; r < 4; ++r)
#pragma unroll
            for (int n = 0; n < 4; ++n)
                Pl[w][(lg * 4 + r) * 72 + n * 16 + lr] = f2bf(p[n][r]);
        __syncthreads();
        b16x8 ap0 = *(const b16x8*)(&Pl[w][lr * 72 + lg * 8]);
        b16x8 ap1 = *(const b16x8*)(&Pl[w][lr * 72 + 32 + lg * 8]);
#pragma unroll
        for (int n = 0; n < 4; ++n) {
            b16x8 bv0 = *(const b16x8*)(&Vt[(n * 16 + lr) * 72 + lg * 8]);
            b16x8 bv1 = *(const b16x8*)(&Vt[(n * 16 + lr) * 72 + 32 + lg * 8]);
            o[n] = __builtin_amdgcn_mfma_f32_16x16x32_bf16(ap0, bv0, o[n], 0, 0, 0);
            o[n] = __builtin_amdgcn_mfma_f32_16x16x32_bf16(ap1, bv1, o[n], 0, 0, 0);
        }
        __syncthreads();
    }
#pragma unroll
    for (int r = 0; r < 4; ++r) {
        float inv = 1.0f / l_run[r];
#pragma unroll
        for (int n = 0; n < 4; ++n)
            aout[(size_t)(tok0 + w * 16 + lg * 4 + r) * 1024 + hoff + n * 16 + lr] =
                f2bf(o[n][r] * inv);
    }
}

// ---------------------------------------------------------------------------
// Launch
// ---------------------------------------------------------------------------
extern "C" void kernel_launch(void* const* d_in, const int* in_sizes, int n_in,
                              void* d_out, int out_size, void* d_ws, size_t ws_size,
                              hipStream_t stream) {
    const float* x1     = (const float*)d_in[0];
    const float* x2     = (const float*)d_in[1];
    const float* w_qkv  = (const float*)d_in[2];
    const float* b_qkv  = (const float*)d_in[3];
    const float* w_proj = (const float*)d_in[4];
    const float* b_proj = (const float*)d_in[5];
    const float* ln1w   = (const float*)d_in[6];
    const float* ln1b   = (const float*)d_in[7];
    const float* ln2w   = (const float*)d_in[8];
    const float* ln2b   = (const float*)d_in[9];
    const float* w_fc1  = (const float*)d_in[10];
    const float* b_fc1  = (const float*)d_in[11];
    const float* w_fc2  = (const float*)d_in[12];
    const float* b_fc2  = (const float*)d_in[13];
    const float* gamma1 = (const float*)d_in[14];
    const float* gamma2 = (const float*)d_in[15];
    float* out = (float*)d_out;
    char* ws = (char*)d_ws;

    // Workspace layout (144 MiB total; all offsets 256B-aligned)
    unsigned short* wqkvT  = (unsigned short*)(ws);              //  6291456 B
    unsigned short* wprojT = (unsigned short*)(ws + 6291456);    //  2097152 B
    unsigned short* wfc1T  = (unsigned short*)(ws + 8388608);    //  8388608 B
    unsigned short* wfc2T  = (unsigned short*)(ws + 16777216);   //  8388608 B
    unsigned short* lnbuf  = (unsigned short*)(ws + 25165824);   // 25165824 B
    unsigned short* qkvbuf = (unsigned short*)(ws + 50331648);   // 75497472 B
    unsigned short* attnbuf= (unsigned short*)(ws + 125829120);  // 25165824 B
    unsigned short* actbuf = (unsigned short*)(ws + 50331648);   // aliases qkv+attn (both dead by then)

    // 1) weights -> bf16, transposed to [N][K]
    wtrans_k<<<dim3(96, 32), 256, 0, stream>>>(w_qkv, wqkvT, 1024, 3072);
    wtrans_k<<<dim3(32, 32), 256, 0, stream>>>(w_proj, wprojT, 1024, 1024);
    wtrans_k<<<dim3(128, 32), 256, 0, stream>>>(w_fc1, wfc1T, 1024, 4096);
    wtrans_k<<<dim3(32, 128), 256, 0, stream>>>(w_fc2, wfc2T, 4096, 1024);
    // 2) LN1 over packed tokens
    ln_k<<<12288, 256, 0, stream>>>(x1, x2, 8192, ln1w, ln1b, lnbuf);
    // 3) qkv = LN1(x) @ w_qkv + b_qkv          [12288,3072] bf16
    gemm2_k<1024, 3072, 0><<<576, 512, 0, stream>>>(lnbuf, wqkvT, b_qkv, nullptr, nullptr,
                                                    nullptr, nullptr, qkvbuf);
    // 4) flash attention -> attnbuf [12288,1024] bf16
    attn_k<<<3072, 256, 0, stream>>>(qkvbuf, attnbuf);
    // 5) y = x + gamma1*(attn @ w_proj + b_proj)  -> d_out f32
    gemm2_k<1024, 1024, 1><<<192, 512, 0, stream>>>(attnbuf, wprojT, b_proj, gamma1, x1, x2,
                                                    out, nullptr);
    // 6) LN2 over y
    ln_k<<<12288, 256, 0, stream>>>(out, out + (size_t)8192 * 1024, 8192, ln2w, ln2b, lnbuf);
    // 7) act = gelu(LN2 @ w_fc1 + b_fc1)        [12288,4096] bf16
    gemm2_k<1024, 4096, 2><<<768, 512, 0, stream>>>(lnbuf, wfc1T, b_fc1, nullptr, nullptr,
                                                    nullptr, nullptr, actbuf);
    // 8) out += gamma2*(act @ w_fc2 + b_fc2)
    gemm2_k<4096, 1024, 3><<<192, 512, 0, stream>>>(actbuf, wfc2T, b_fc2, gamma2, nullptr,
                                                    nullptr, out, nullptr);
}

// Round 3
// 654.839 us; speedup vs baseline: 1.1016x; 1.0526x over previous
//
#include <hip/hip_runtime.h>
#include <cstddef>

// ---------------------------------------------------------------------------
// NestedTensorBlock (ViT block) on MI355X.
// D=1024, H=16, HD=64. Tokens: x1 8x1024 (tok 0..8191), x2 8x512 (tok 8192..12287).
// GEMMs: 256x256-tile, 8-wave, BK=32, 4-slot LDS ring, depth-3 prefetch, counted vmcnt.
// Attention: 8-wave blocks, Q-tile 128, KVBLK 64 double-buffered via global_load_lds
// with XOR-swizzled sources (linear LDS dest), V pre-transposed by vtrans_k,
// exp2-domain online softmax, per-wave P tile (no barrier between P write/read).
// ---------------------------------------------------------------------------

typedef __bf16 b16x8 __attribute__((ext_vector_type(8)));
typedef float f32x4 __attribute__((ext_vector_type(4)));
typedef unsigned short u16x8 __attribute__((ext_vector_type(8)));
typedef unsigned short u16x4 __attribute__((ext_vector_type(4)));
typedef float f32x4v __attribute__((ext_vector_type(4)));

__device__ __forceinline__ unsigned short f2bf(float f) {
    unsigned int u = __builtin_bit_cast(unsigned int, f);
    return (unsigned short)((u + 0x7fffu + ((u >> 16) & 1u)) >> 16);
}

__device__ __forceinline__ float exp2_f(float x) {
#if defined(__has_builtin)
#if __has_builtin(__builtin_amdgcn_exp2f)
    return __builtin_amdgcn_exp2f(x);
#else
    return exp2f(x);
#endif
#else
    return exp2f(x);
#endif
}

#define AS1C(p) ((const __attribute__((address_space(1))) void*)(p))
#define AS3(p)  ((__attribute__((address_space(3))) void*)(p))
#define FENCE() asm volatile("" ::: "memory")

// ---------------------------------------------------------------------------
// Weight transpose + f32->bf16:  in [K][N] f32  ->  out [N][K] bf16
// ---------------------------------------------------------------------------
__global__ __launch_bounds__(256) void wtrans_k(const float* __restrict__ in,
                                                unsigned short* __restrict__ out,
                                                int K, int N) {
    __shared__ float tile[32][33];
    int n0 = blockIdx.x << 5, k0 = blockIdx.y << 5;
    int tx = threadIdx.x & 31;
    int ty = threadIdx.x >> 5;  // 0..7
#pragma unroll
    for (int j = 0; j < 4; ++j)
        tile[ty + j * 8][tx] = in[(size_t)(k0 + ty + j * 8) * N + n0 + tx];
    __syncthreads();
#pragma unroll
    for (int j = 0; j < 4; ++j)
        out[(size_t)(n0 + ty + j * 8) * K + k0 + tx] = f2bf(tile[tx][ty + j * 8]);
}

// ---------------------------------------------------------------------------
// V transpose: qkv[tok][2048+c] (bf16) -> vT[c][tok], c in [0,1024)
// ---------------------------------------------------------------------------
__global__ __launch_bounds__(256) void vtrans_k(const unsigned short* __restrict__ qkv,
                                                unsigned short* __restrict__ vT) {
    __shared__ unsigned short tile[32][40];
    int tok0 = blockIdx.x << 5, c0 = blockIdx.y << 5;
    int tx = threadIdx.x & 31, ty = threadIdx.x >> 5;
#pragma unroll
    for (int j = 0; j < 4; ++j)
        tile[ty + j * 8][tx] = qkv[(size_t)(tok0 + ty + j * 8) * 3072 + 2048 + c0 + tx];
    __syncthreads();
#pragma unroll
    for (int j = 0; j < 4; ++j)
        vT[(size_t)(c0 + ty + j * 8) * 12288 + tok0 + tx] = tile[tx][ty + j * 8];
}

// ---------------------------------------------------------------------------
// LayerNorm: row in {srcA (row<split) | srcB}, 1024 cols -> bf16 out
// ---------------------------------------------------------------------------
__global__ __launch_bounds__(256) void ln_k(const float* __restrict__ srcA,
                                            const float* __restrict__ srcB, int split,
                                            const float* __restrict__ w,
                                            const float* __restrict__ b,
                                            unsigned short* __restrict__ out) {
    int row = blockIdx.x;
    const float* src = (row < split) ? srcA + (size_t)row * 1024
                                     : srcB + (size_t)(row - split) * 1024;
    int t = threadIdx.x;
    f32x4v v = *(const f32x4v*)(src + t * 4);
    float s = v[0] + v[1] + v[2] + v[3];
    float s2 = v[0] * v[0] + v[1] * v[1] + v[2] * v[2] + v[3] * v[3];
#pragma unroll
    for (int off = 1; off < 64; off <<= 1) {
        s += __shfl_xor(s, off);
        s2 += __shfl_xor(s2, off);
    }
    __shared__ float red[8];
    int wv4 = t >> 6;
    if ((t & 63) == 0) { red[wv4 * 2] = s; red[wv4 * 2 + 1] = s2; }
    __syncthreads();
    s = red[0] + red[2] + red[4] + red[6];
    s2 = red[1] + red[3] + red[5] + red[7];
    float mean = s * (1.0f / 1024.0f);
    float var = s2 * (1.0f / 1024.0f) - mean * mean;
    float rstd = rsqrtf(var + 1e-5f);
    f32x4v wv = *(const f32x4v*)(w + t * 4);
    f32x4v bv = *(const f32x4v*)(b + t * 4);
    u16x4 ov;
#pragma unroll
    for (int j = 0; j < 4; ++j) ov[j] = f2bf((v[j] - mean) * rstd * wv[j] + bv[j]);
    *(u16x4*)(out + (size_t)row * 1024 + t * 4) = ov;
}

// ---------------------------------------------------------------------------
// 256x256-tile bf16 GEMM (unchanged from round 2)
// ---------------------------------------------------------------------------
template <int K, int NN, int EPI>
__global__ __launch_bounds__(512, 2) void gemm2_k(
    const unsigned short* __restrict__ A, const unsigned short* __restrict__ BT,
    const float* __restrict__ bias, const float* __restrict__ scale,
    const float* __restrict__ rx1, const float* __restrict__ rx2,
    float* __restrict__ outf, unsigned short* __restrict__ outb) {
    __shared__ char lds[131072];
    constexpr int NT = K / 32;
    constexpr int ntn = NN >> 8;
    const int t = threadIdx.x;
    const int lane = t & 63, w = t >> 6, lr = lane & 15, lg = lane >> 4;
    const int wm = w >> 2, wn = w & 3;
    const int nwg = gridDim.x;
    const int bid = blockIdx.x;
    const int swz = (bid & 7) * (nwg >> 3) + (bid >> 3);
    const int m0 = (swz / ntn) << 8;
    const int n0 = (swz % ntn) << 8;

    const unsigned short* gA0 = A + (size_t)(m0 + (t >> 2)) * K + (t & 3) * 8;
    const unsigned short* gA1 = gA0 + (size_t)128 * K;
    const unsigned short* gB0 = BT + (size_t)(n0 + (t >> 2)) * K + (t & 3) * 8;
    const unsigned short* gB1 = gB0 + (size_t)128 * K;
    const int wbase = w * 1024;

    f32x4 acc[8][4] = {};

    auto STAGE = [&](int kt) {
        char* sb = lds + (kt & 3) * 32768;
        int ko = kt * 32;
        __builtin_amdgcn_global_load_lds(AS1C(gA0 + ko), AS3(sb + wbase), 16, 0, 0);
        __builtin_amdgcn_global_load_lds(AS1C(gA1 + ko), AS3(sb + 8192 + wbase), 16, 0, 0);
        __builtin_amdgcn_global_load_lds(AS1C(gB0 + ko), AS3(sb + 16384 + wbase), 16, 0, 0);
        __builtin_amdgcn_global_load_lds(AS1C(gB1 + ko), AS3(sb + 24576 + wbase), 16, 0, 0);
    };
    auto COMPUTE = [&](int kt) {
        const char* sa = lds + (kt & 3) * 32768 + (wm * 128 + lr) * 64 + lg * 16;
        const char* sq = lds + (kt & 3) * 32768 + 16384 + (wn * 64 + lr) * 64 + lg * 16;
        b16x8 af[8], bf[4];
#pragma unroll
        for (int m = 0; m < 8; ++m) af[m] = *(const b16x8*)(sa + m * 1024);
#pragma unroll
        for (int n = 0; n < 4; ++n) bf[n] = *(const b16x8*)(sq + n * 1024);
        __builtin_amdgcn_s_setprio(1);
#pragma unroll
        for (int m = 0; m < 8; ++m)
#pragma unroll
            for (int n = 0; n < 4; ++n)
                acc[m][n] = __builtin_amdgcn_mfma_f32_16x16x32_bf16(af[m], bf[n], acc[m][n], 0, 0, 0);
        __builtin_amdgcn_s_setprio(0);
    };

    STAGE(0); STAGE(1); STAGE(2);
    for (int kt = 0; kt < NT - 3; ++kt) {
        STAGE(kt + 3);
        asm volatile("s_waitcnt vmcnt(12)" ::: "memory");
        __builtin_amdgcn_s_barrier();
        FENCE();
        COMPUTE(kt);
        FENCE();
        __builtin_amdgcn_s_barrier();
        FENCE();
    }
    asm volatile("s_waitcnt vmcnt(8)" ::: "memory");
    __builtin_amdgcn_s_barrier(); FENCE();
    COMPUTE(NT - 3); FENCE();
    __builtin_amdgcn_s_barrier(); FENCE();
    asm volatile("s_waitcnt vmcnt(4)" ::: "memory");
    __builtin_amdgcn_s_barrier(); FENCE();
    COMPUTE(NT - 2); FENCE();
    __builtin_amdgcn_s_barrier(); FENCE();
    asm volatile("s_waitcnt vmcnt(0)" ::: "memory");
    __builtin_amdgcn_s_barrier(); FENCE();
    COMPUTE(NT - 1);

    const int rbase = m0 + wm * 128 + lg * 4;
    const int cbase = n0 + wn * 64 + lr;
#pragma unroll
    for (int n = 0; n < 4; ++n) {
        int col = cbase + n * 16;
        float bval = bias[col];
        float sval = (EPI == 1 || EPI == 3) ? scale[col] : 0.f;
#pragma unroll
        for (int m = 0; m < 8; ++m) {
            int row = rbase + m * 16;
#pragma unroll
            for (int r = 0; r < 4; ++r) {
                float c = acc[m][n][r] + bval;
                size_t idx = (size_t)(row + r) * NN + col;
                if (EPI == 0) {
                    outb[idx] = f2bf(c);
                } else if (EPI == 1) {
                    float xv = (row + r < 8192) ? rx1[idx] : rx2[idx - (size_t)8192 * 1024];
                    outf[idx] = xv + sval * c;
                } else if (EPI == 2) {
                    float u = c * (c * c * 0.044715f + 1.0f) * 1.5957691216057308f;
                    outb[idx] = f2bf(c / (1.0f + __expf(-u)));
                } else {
                    outf[idx] += sval * c;
                }
            }
        }
    }
}

// ---------------------------------------------------------------------------
// Flash attention v2: one block = (seq, head, 128-row Q tile), 8 waves.
// K staged from qkv (rows=kv tokens), V staged from vT (rows=hd) — both [64][128B]
// via global_load_lds with XOR-swizzled global source; ds_read applies same XOR.
// Double-buffered slots, counted vmcnt(2). exp2-domain online softmax.
// ---------------------------------------------------------------------------
__global__ __launch_bounds__(512) void attn_k(const unsigned short* __restrict__ qkv,
                                              const unsigned short* __restrict__ vT,
                                              unsigned short* __restrict__ aout) {
    __shared__ char sK[2][8192];
    __shared__ char sV[2][8192];
    __shared__ unsigned short sP[8][16 * 72];
    int bid = blockIdx.x;
    int t = threadIdx.x, lane = t & 63, w = t >> 6, lr = lane & 15, lg = lane >> 4;
    int seq0, S, h, qt;
    if (bid < 1024) {  // x1: 8 seqs * 16 heads * 8 qtiles
        int b = bid >> 7, r = bid & 127;
        h = r >> 3; qt = r & 7; seq0 = b << 10; S = 1024;
    } else {           // x2: 8 seqs * 16 heads * 4 qtiles
        int i2 = bid - 1024;
        int b = i2 >> 6, r = i2 & 63;
        h = r >> 2; qt = r & 3; seq0 = 8192 + (b << 9); S = 512;
    }
    int tok0 = seq0 + qt * 128;
    const size_t hoff = (size_t)h * 64;

    // staging: thread t covers 16B chunk (row = t>>3, chunk = t&7) of a [64][128B] tile;
    // source chunk is XOR-swizzled so that LDS_linear[row][s] = G[row][s ^ (row&7)].
    const int srow = t >> 3;
    const int sc = ((t & 7) ^ (srow & 7)) * 8;  // shorts
    const unsigned short* kg = qkv + (size_t)(seq0 + srow) * 3072 + 1024 + hoff + sc;
    const unsigned short* vg = vT + (size_t)(hoff + srow) * 12288 + seq0 + sc;

    // Q fragments (held in registers for the whole block)
    b16x8 aq0, aq1;
    {
        const unsigned short* qb = qkv + (size_t)(tok0 + w * 16 + lr) * 3072 + hoff;
        aq0 = *(const b16x8*)(qb + lg * 8);
        aq1 = *(const b16x8*)(qb + 32 + lg * 8);
    }

    auto STAGE = [&](int kt) {
        int slot = kt & 1;
        __builtin_amdgcn_global_load_lds(AS1C(kg + (size_t)(kt << 6) * 3072),
                                         AS3(sK[slot] + t * 16), 16, 0, 0);
        __builtin_amdgcn_global_load_lds(AS1C(vg + (kt << 6)),
                                         AS3(sV[slot] + t * 16), 16, 0, 0);
    };

    const int swz0 = (lg ^ (lr & 7)) * 16;        // byte offset of k-chunk lg, deswizzled
    const int swz1 = ((4 + lg) ^ (lr & 7)) * 16;  // k-chunk 4+lg
    const float SC = 0.18033688f;  // 0.125 * log2(e)

    float m_run[4] = {-1e30f, -1e30f, -1e30f, -1e30f};
    float l_run[4] = {0.f, 0.f, 0.f, 0.f};
    f32x4 o[4] = {};
    unsigned short* sPw = sP[w];
    int nkv = S >> 6;

    STAGE(0);
    for (int kt = 0; kt < nkv; ++kt) {
        if (kt + 1 < nkv) {
            STAGE(kt + 1);
            asm volatile("s_waitcnt vmcnt(2)" ::: "memory");  // slot kt landed (this wave)
        } else {
            asm volatile("s_waitcnt vmcnt(0)" ::: "memory");
        }
        __builtin_amdgcn_s_barrier();  // ...and all waves
        FENCE();
        const char* kb = sK[kt & 1];
        const char* vb = sV[kt & 1];
        // QK^T
        f32x4 s[4];
#pragma unroll
        for (int n = 0; n < 4; ++n) {
            const char* kr = kb + (n * 16 + lr) * 128;
            b16x8 bk0 = *(const b16x8*)(kr + swz0);
            b16x8 bk1 = *(const b16x8*)(kr + swz1);
            f32x4 z = {};
            z = __builtin_amdgcn_mfma_f32_16x16x32_bf16(aq0, bk0, z, 0, 0, 0);
            z = __builtin_amdgcn_mfma_f32_16x16x32_bf16(aq1, bk1, z, 0, 0, 0);
            s[n] = z * SC;  // exp2 domain
        }
        // online softmax (rows q = lg*4+r, cols kv = n*16+lr)
        float p[4][4];
#pragma unroll
        for (int r = 0; r < 4; ++r) {
            float tm = fmaxf(fmaxf(s[0][r], s[1][r]), fmaxf(s[2][r], s[3][r]));
            tm = fmaxf(tm, __shfl_xor(tm, 1));
            tm = fmaxf(tm, __shfl_xor(tm, 2));
            tm = fmaxf(tm, __shfl_xor(tm, 4));
            tm = fmaxf(tm, __shfl_xor(tm, 8));
            float mn = fmaxf(m_run[r], tm);
            float alpha = exp2_f(m_run[r] - mn);
            m_run[r] = mn;
            float rs = 0.f;
#pragma unroll
            for (int n = 0; n < 4; ++n) {
                float pv = exp2_f(s[n][r] - mn);
                p[n][r] = pv;
                rs += pv;
            }
            rs += __shfl_xor(rs, 1);
            rs += __shfl_xor(rs, 2);
            rs += __shfl_xor(rs, 4);
            rs += __shfl_xor(rs, 8);
            l_run[r] = l_run[r] * alpha + rs;
#pragma unroll
            for (int n = 0; n < 4; ++n) o[n][r] *= alpha;
        }
        // P -> per-wave LDS tile (no barrier needed: same wave reads it back)
#pragma unroll
        for (int r = 0; r < 4; ++r)
#pragma unroll
            for (int n = 0; n < 4; ++n)
                sPw[(lg * 4 + r) * 72 + n * 16 + lr] = f2bf(p[n][r]);
        b16x8 ap0 = *(const b16x8*)(&sPw[lr * 72 + lg * 8]);
        b16x8 ap1 = *(const b16x8*)(&sPw[lr * 72 + 32 + lg * 8]);
        // PV
#pragma unroll
        for (int n = 0; n < 4; ++n) {
            const char* vr = vb + (n * 16 + lr) * 128;
            b16x8 bv0 = *(const b16x8*)(vr + swz0);
            b16x8 bv1 = *(const b16x8*)(vr + swz1);
            o[n] = __builtin_amdgcn_mfma_f32_16x16x32_bf16(ap0, bv0, o[n], 0, 0, 0);
            o[n] = __builtin_amdgcn_mfma_f32_16x16x32_bf16(ap1, bv1, o[n], 0, 0, 0);
        }
        FENCE();
        if (kt + 1 < nkv) __builtin_amdgcn_s_barrier();  // slot kt free for overwrite
        FENCE();
    }
#pragma unroll
    for (int r = 0; r < 4; ++r) {
        float inv = 1.0f / l_run[r];
#pragma unroll
        for (int n = 0; n < 4; ++n)
            aout[(size_t)(tok0 + w * 16 + lg * 4 + r) * 1024 + hoff + n * 16 + lr] =
                f2bf(o[n][r] * inv);
    }
}

// ---------------------------------------------------------------------------
// Launch
// ---------------------------------------------------------------------------
extern "C" void kernel_launch(void* const* d_in, const int* in_sizes, int n_in,
                              void* d_out, int out_size, void* d_ws, size_t ws_size,
                              hipStream_t stream) {
    const float* x1     = (const float*)d_in[0];
    const float* x2     = (const float*)d_in[1];
    const float* w_qkv  = (const float*)d_in[2];
    const float* b_qkv  = (const float*)d_in[3];
    const float* w_proj = (const float*)d_in[4];
    const float* b_proj = (const float*)d_in[5];
    const float* ln1w   = (const float*)d_in[6];
    const float* ln1b   = (const float*)d_in[7];
    const float* ln2w   = (const float*)d_in[8];
    const float* ln2b   = (const float*)d_in[9];
    const float* w_fc1  = (const float*)d_in[10];
    const float* b_fc1  = (const float*)d_in[11];
    const float* w_fc2  = (const float*)d_in[12];
    const float* b_fc2  = (const float*)d_in[13];
    const float* gamma1 = (const float*)d_in[14];
    const float* gamma2 = (const float*)d_in[15];
    float* out = (float*)d_out;
    char* ws = (char*)d_ws;

    // Workspace layout (144 MiB total)
    unsigned short* wqkvT  = (unsigned short*)(ws);              //  6291456 B
    unsigned short* wprojT = (unsigned short*)(ws + 6291456);    //  2097152 B
    unsigned short* wfc1T  = (unsigned short*)(ws + 8388608);    //  8388608 B
    unsigned short* wfc2T  = (unsigned short*)(ws + 16777216);   //  8388608 B
    unsigned short* lnbuf  = (unsigned short*)(ws + 25165824);   // 25165824 B (also vT after qkv GEMM)
    unsigned short* qkvbuf = (unsigned short*)(ws + 50331648);   // 75497472 B
    unsigned short* attnbuf= (unsigned short*)(ws + 125829120);  // 25165824 B
    unsigned short* actbuf = (unsigned short*)(ws + 50331648);   // aliases qkv+attn (both dead by then)
    unsigned short* vTbuf  = lnbuf;                              // 1024 x 12288 bf16 (LN1 out dead)

    // 1) weights -> bf16, transposed to [N][K]
    wtrans_k<<<dim3(96, 32), 256, 0, stream>>>(w_qkv, wqkvT, 1024, 3072);
    wtrans_k<<<dim3(32, 32), 256, 0, stream>>>(w_proj, wprojT, 1024, 1024);
    wtrans_k<<<dim3(128, 32), 256, 0, stream>>>(w_fc1, wfc1T, 1024, 4096);
    wtrans_k<<<dim3(32, 128), 256, 0, stream>>>(w_fc2, wfc2T, 4096, 1024);
    // 2) LN1 over packed tokens
    ln_k<<<12288, 256, 0, stream>>>(x1, x2, 8192, ln1w, ln1b, lnbuf);
    // 3) qkv = LN1(x) @ w_qkv + b_qkv          [12288,3072] bf16
    gemm2_k<1024, 3072, 0><<<576, 512, 0, stream>>>(lnbuf, wqkvT, b_qkv, nullptr, nullptr,
                                                    nullptr, nullptr, qkvbuf);
    // 3b) vT[c][tok] = V part of qkv (lnbuf is dead now; reuse as vT)
    vtrans_k<<<dim3(384, 32), 256, 0, stream>>>(qkvbuf, vTbuf);
    // 4) flash attention -> attnbuf [12288,1024] bf16
    attn_k<<<1536, 512, 0, stream>>>(qkvbuf, vTbuf, attnbuf);
    // 5) y = x + gamma1*(attn @ w_proj + b_proj)  -> d_out f32
    gemm2_k<1024, 1024, 1><<<192, 512, 0, stream>>>(attnbuf, wprojT, b_proj, gamma1, x1, x2,
                                                    out, nullptr);
    // 6) LN2 over y
    ln_k<<<12288, 256, 0, stream>>>(out, out + (size_t)8192 * 1024, 8192, ln2w, ln2b, lnbuf);
    // 7) act = gelu(LN2 @ w_fc1 + b_fc1)        [12288,4096] bf16
    gemm2_k<1024, 4096, 2><<<768, 512, 0, stream>>>(lnbuf, wfc1T, b_fc1, nullptr, nullptr,
                                                    nullptr, nullptr, actbuf);
    // 8) out += gamma2*(act @ w_fc2 + b_fc2)
    gemm2_k<4096, 1024, 3><<<192, 512, 0, stream>>>(actbuf, wfc2T, b_fc2, gamma2, nullptr,
                                                    nullptr, out, nullptr);
}

// Round 4
// 632.686 us; speedup vs baseline: 1.1401x; 1.0350x over previous
//
#include <hip/hip_runtime.h>
#include <cstddef>

// ---------------------------------------------------------------------------
// NestedTensorBlock (ViT block) on MI355X.
// D=1024, H=16, HD=64. Tokens: x1 8x1024 (tok 0..8191), x2 8x512 (tok 8192..12287).
// GEMMs: 256x256 tile, BK=64, 8-phase schedule (4 phases/K-tile, 16 MFMA each),
// 2 LDS buffers w/ XOR-swizzled storage (linear dest + inverse-swizzled global
// source + swizzled ds_read), counted vmcnt(4) once per tile, setprio on MFMA.
// Attention: 8-wave flash kernel (round-3, unchanged).
// ---------------------------------------------------------------------------

typedef __bf16 b16x8 __attribute__((ext_vector_type(8)));
typedef float f32x4 __attribute__((ext_vector_type(4)));
typedef unsigned short u16x8 __attribute__((ext_vector_type(8)));
typedef unsigned short u16x4 __attribute__((ext_vector_type(4)));
typedef float f32x4v __attribute__((ext_vector_type(4)));

__device__ __forceinline__ unsigned short f2bf(float f) {
    unsigned int u = __builtin_bit_cast(unsigned int, f);
    return (unsigned short)((u + 0x7fffu + ((u >> 16) & 1u)) >> 16);
}

__device__ __forceinline__ float exp2_f(float x) {
#if defined(__has_builtin)
#if __has_builtin(__builtin_amdgcn_exp2f)
    return __builtin_amdgcn_exp2f(x);
#else
    return exp2f(x);
#endif
#else
    return exp2f(x);
#endif
}

#define AS1C(p) ((const __attribute__((address_space(1))) void*)(p))
#define AS3(p)  ((__attribute__((address_space(3))) void*)(p))
#define FENCE() asm volatile("" ::: "memory")

// ---------------------------------------------------------------------------
// Weight transpose + f32->bf16:  in [K][N] f32  ->  out [N][K] bf16
// ---------------------------------------------------------------------------
__global__ __launch_bounds__(256) void wtrans_k(const float* __restrict__ in,
                                                unsigned short* __restrict__ out,
                                                int K, int N) {
    __shared__ float tile[32][33];
    int n0 = blockIdx.x << 5, k0 = blockIdx.y << 5;
    int tx = threadIdx.x & 31;
    int ty = threadIdx.x >> 5;  // 0..7
#pragma unroll
    for (int j = 0; j < 4; ++j)
        tile[ty + j * 8][tx] = in[(size_t)(k0 + ty + j * 8) * N + n0 + tx];
    __syncthreads();
#pragma unroll
    for (int j = 0; j < 4; ++j)
        out[(size_t)(n0 + ty + j * 8) * K + k0 + tx] = f2bf(tile[tx][ty + j * 8]);
}

// ---------------------------------------------------------------------------
// V transpose: qkv[tok][2048+c] (bf16) -> vT[c][tok], c in [0,1024)
// ---------------------------------------------------------------------------
__global__ __launch_bounds__(256) void vtrans_k(const unsigned short* __restrict__ qkv,
                                                unsigned short* __restrict__ vT) {
    __shared__ unsigned short tile[32][40];
    int tok0 = blockIdx.x << 5, c0 = blockIdx.y << 5;
    int tx = threadIdx.x & 31, ty = threadIdx.x >> 5;
#pragma unroll
    for (int j = 0; j < 4; ++j)
        tile[ty + j * 8][tx] = qkv[(size_t)(tok0 + ty + j * 8) * 3072 + 2048 + c0 + tx];
    __syncthreads();
#pragma unroll
    for (int j = 0; j < 4; ++j)
        vT[(size_t)(c0 + ty + j * 8) * 12288 + tok0 + tx] = tile[tx][ty + j * 8];
}

// ---------------------------------------------------------------------------
// LayerNorm: row in {srcA (row<split) | srcB}, 1024 cols -> bf16 out
// ---------------------------------------------------------------------------
__global__ __launch_bounds__(256) void ln_k(const float* __restrict__ srcA,
                                            const float* __restrict__ srcB, int split,
                                            const float* __restrict__ w,
                                            const float* __restrict__ b,
                                            unsigned short* __restrict__ out) {
    int row = blockIdx.x;
    const float* src = (row < split) ? srcA + (size_t)row * 1024
                                     : srcB + (size_t)(row - split) * 1024;
    int t = threadIdx.x;
    f32x4v v = *(const f32x4v*)(src + t * 4);
    float s = v[0] + v[1] + v[2] + v[3];
    float s2 = v[0] * v[0] + v[1] * v[1] + v[2] * v[2] + v[3] * v[3];
#pragma unroll
    for (int off = 1; off < 64; off <<= 1) {
        s += __shfl_xor(s, off);
        s2 += __shfl_xor(s2, off);
    }
    __shared__ float red[8];
    int wv4 = t >> 6;
    if ((t & 63) == 0) { red[wv4 * 2] = s; red[wv4 * 2 + 1] = s2; }
    __syncthreads();
    s = red[0] + red[2] + red[4] + red[6];
    s2 = red[1] + red[3] + red[5] + red[7];
    float mean = s * (1.0f / 1024.0f);
    float var = s2 * (1.0f / 1024.0f) - mean * mean;
    float rstd = rsqrtf(var + 1e-5f);
    f32x4v wv = *(const f32x4v*)(w + t * 4);
    f32x4v bv = *(const f32x4v*)(b + t * 4);
    u16x4 ov;
#pragma unroll
    for (int j = 0; j < 4; ++j) ov[j] = f2bf((v[j] - mean) * rstd * wv[j] + bv[j]);
    *(u16x4*)(out + (size_t)row * 1024 + t * 4) = ov;
}

// ---------------------------------------------------------------------------
// 8-phase 256x256 bf16 GEMM: C[M,NN] = A[M,K]*BT[NN,K]^T (+bias, epilogue EPI)
// 512 thr = 8 waves (2M x 4N); per-wave C = 128x64 = 8x4 16x16 frags.
// BK=64; LDS = 2 buf x (A 32KB + B 32KB) = 128 KiB.
// LDS storage swizzle: 16B chunk p of row r holds global chunk p^(r&7)
// (conflict-free ds_read_b128 columns; staging stays linear-dest).
// Per K-tile: 4 phases x {ds_read, stage-issue, bar, MFMA x16, bar};
// stage units (2 loads) at phases A,B,(D x2); vmcnt(4) once per tile.
// EPI: 0 = store bf16 (qkv)          1 = out_f32 = x + gamma1*C (proj)
//      2 = store bf16(gelu(C)) (fc1) 3 = out_f32 += gamma2*C (fc2)
// ---------------------------------------------------------------------------
template <int K, int NN, int EPI>
__global__ __launch_bounds__(512, 1) void gemm3_k(
    const unsigned short* __restrict__ A, const unsigned short* __restrict__ BT,
    const float* __restrict__ bias, const float* __restrict__ scale,
    const float* __restrict__ rx1, const float* __restrict__ rx2,
    float* __restrict__ outf, unsigned short* __restrict__ outb) {
    __shared__ char lds[131072];
    constexpr int NT = K / 64;
    constexpr int ntn = NN >> 8;
    const int t = threadIdx.x;
    const int lane = t & 63, w = t >> 6, lr = lane & 15, lg = lane >> 4;
    const int wm = w >> 2, wn = w & 3;
    const int nwg = gridDim.x;
    const int bid = blockIdx.x;
    const int swz = (bid & 7) * (nwg >> 3) + (bid >> 3);
    const int m0 = (swz / ntn) << 8;
    const int n0 = (swz % ntn) << 8;

    // staging source (per-thread): row = t>>3 (of 64 per issue), chunk p = t&7;
    // fetch global chunk p^(row&7) so linear LDS ends up swizzle-stored.
    const int srow = t >> 3;
    const int scol = ((t & 7) ^ (srow & 7)) * 8;  // shorts
    const unsigned short* ga = A + (size_t)(m0 + srow) * K + scol;
    const unsigned short* gb = BT + (size_t)(n0 + srow) * K + scol;

    f32x4 acc[8][4] = {};
    b16x8 af[4][2], b01[2][2], b23[2][2];

    // unit: 0 = A rows 0-127, 1 = A rows 128-255, 2 = B rows 0-127, 3 = B 128-255
    auto ISSUE = [&](int tile, int unit) {
        char* dst = lds + (tile & 1) * 65536 + unit * 16384 + t * 16;
        const unsigned short* src = (unit < 2 ? ga : gb) +
                                    (size_t)((unit & 1) * 128) * K + tile * 64;
        __builtin_amdgcn_global_load_lds(AS1C(src), AS3(dst), 16, 0, 0);
        __builtin_amdgcn_global_load_lds(AS1C(src + (size_t)64 * K), AS3(dst + 8192), 16, 0, 0);
    };

    const int cs0 = (lg ^ (lr & 7)) * 16;        // kk=0 chunk, deswizzled (byte)
    const int cs1 = ((4 + lg) ^ (lr & 7)) * 16;  // kk=1 chunk

    auto RD_A = [&](const char* buf, int mg) {
#pragma unroll
        for (int mi = 0; mi < 4; ++mi) {
            const char* p = buf + (wm * 128 + (mg + mi) * 16 + lr) * 128;
            af[mi][0] = *(const b16x8*)(p + cs0);
            af[mi][1] = *(const b16x8*)(p + cs1);
        }
    };
    auto RD_B = [&](const char* buf, b16x8 (*bf)[2], int ng) {
#pragma unroll
        for (int ni = 0; ni < 2; ++ni) {
            const char* p = buf + 32768 + (wn * 64 + (ng + ni) * 16 + lr) * 128;
            bf[ni][0] = *(const b16x8*)(p + cs0);
            bf[ni][1] = *(const b16x8*)(p + cs1);
        }
    };
    auto MM = [&](int mg, b16x8 (*bf)[2], int ng) {
        __builtin_amdgcn_s_setprio(1);
#pragma unroll
        for (int mi = 0; mi < 4; ++mi)
#pragma unroll
            for (int ni = 0; ni < 2; ++ni)
#pragma unroll
                for (int kk = 0; kk < 2; ++kk)
                    acc[mg + mi][ng + ni] = __builtin_amdgcn_mfma_f32_16x16x32_bf16(
                        af[mi][kk], bf[ni][kk], acc[mg + mi][ng + ni], 0, 0, 0);
        __builtin_amdgcn_s_setprio(0);
    };

    // prologue: tile0 fully + tile1 A-halves; tile0 guaranteed landed (vmcnt(4))
    ISSUE(0, 0); ISSUE(0, 1); ISSUE(0, 2); ISSUE(0, 3);
    ISSUE(1, 0); ISSUE(1, 1);
    asm volatile("s_waitcnt vmcnt(4)" ::: "memory");
    __builtin_amdgcn_s_barrier();
    FENCE();

    for (int kt = 0; kt < NT; ++kt) {
        const char* buf = lds + (kt & 1) * 65536;
        // phase A: m0-3 x n0-1
        RD_A(buf, 0); RD_B(buf, b01, 0);
        if (kt + 1 < NT) ISSUE(kt + 1, 2);
        __builtin_amdgcn_s_barrier(); FENCE();
        MM(0, b01, 0);
        __builtin_amdgcn_s_barrier(); FENCE();
        // phase B: m0-3 x n2-3
        RD_B(buf, b23, 2);
        if (kt + 1 < NT) ISSUE(kt + 1, 3);
        __builtin_amdgcn_s_barrier(); FENCE();
        MM(0, b23, 2);
        __builtin_amdgcn_s_barrier(); FENCE();
        // phase C: m4-7 x n2-3
        RD_A(buf, 4);
        __builtin_amdgcn_s_barrier(); FENCE();
        MM(4, b23, 2);
        __builtin_amdgcn_s_barrier(); FENCE();
        // phase D: m4-7 x n0-1 (no reads; safe to overwrite this buf's A-region)
        if (kt + 2 < NT) { ISSUE(kt + 2, 0); ISSUE(kt + 2, 1); }
        __builtin_amdgcn_s_barrier(); FENCE();
        MM(4, b01, 0);
        if (kt + 1 < NT) {
            if (kt < NT - 2) asm volatile("s_waitcnt vmcnt(4)" ::: "memory");
            else             asm volatile("s_waitcnt vmcnt(0)" ::: "memory");
            __builtin_amdgcn_s_barrier(); FENCE();
        }
    }

    // epilogue
    const int rbase = m0 + wm * 128 + lg * 4;
    const int cbase = n0 + wn * 64 + lr;
#pragma unroll
    for (int n = 0; n < 4; ++n) {
        int col = cbase + n * 16;
        float bval = bias[col];
        float sval = (EPI == 1 || EPI == 3) ? scale[col] : 0.f;
#pragma unroll
        for (int m = 0; m < 8; ++m) {
            int row = rbase + m * 16;
#pragma unroll
            for (int r = 0; r < 4; ++r) {
                float c = acc[m][n][r] + bval;
                size_t idx = (size_t)(row + r) * NN + col;
                if (EPI == 0) {
                    outb[idx] = f2bf(c);
                } else if (EPI == 1) {
                    float xv = (row + r < 8192) ? rx1[idx] : rx2[idx - (size_t)8192 * 1024];
                    outf[idx] = xv + sval * c;
                } else if (EPI == 2) {
                    float u = c * (c * c * 0.044715f + 1.0f) * 1.5957691216057308f;
                    outb[idx] = f2bf(c / (1.0f + __expf(-u)));
                } else {
                    outf[idx] += sval * c;
                }
            }
        }
    }
}

// ---------------------------------------------------------------------------
// Flash attention: one block = (seq, head, 128-row Q tile), 8 waves.
// K staged from qkv, V staged from vT — both [64][128B] via global_load_lds
// with XOR-swizzled sources; ds_read applies same XOR. Double-buffered,
// counted vmcnt(2). exp2-domain online softmax. (round-3, unchanged)
// ---------------------------------------------------------------------------
__global__ __launch_bounds__(512) void attn_k(const unsigned short* __restrict__ qkv,
                                              const unsigned short* __restrict__ vT,
                                              unsigned short* __restrict__ aout) {
    __shared__ char sK[2][8192];
    __shared__ char sV[2][8192];
    __shared__ unsigned short sP[8][16 * 72];
    int bid = blockIdx.x;
    int t = threadIdx.x, lane = t & 63, w = t >> 6, lr = lane & 15, lg = lane >> 4;
    int seq0, S, h, qt;
    if (bid < 1024) {
        int b = bid >> 7, r = bid & 127;
        h = r >> 3; qt = r & 7; seq0 = b << 10; S = 1024;
    } else {
        int i2 = bid - 1024;
        int b = i2 >> 6, r = i2 & 63;
        h = r >> 2; qt = r & 3; seq0 = 8192 + (b << 9); S = 512;
    }
    int tok0 = seq0 + qt * 128;
    const size_t hoff = (size_t)h * 64;

    const int srow = t >> 3;
    const int sc = ((t & 7) ^ (srow & 7)) * 8;
    const unsigned short* kg = qkv + (size_t)(seq0 + srow) * 3072 + 1024 + hoff + sc;
    const unsigned short* vg = vT + (size_t)(hoff + srow) * 12288 + seq0 + sc;

    b16x8 aq0, aq1;
    {
        const unsigned short* qb = qkv + (size_t)(tok0 + w * 16 + lr) * 3072 + hoff;
        aq0 = *(const b16x8*)(qb + lg * 8);
        aq1 = *(const b16x8*)(qb + 32 + lg * 8);
    }

    auto STAGE = [&](int kt) {
        int slot = kt & 1;
        __builtin_amdgcn_global_load_lds(AS1C(kg + (size_t)(kt << 6) * 3072),
                                         AS3(sK[slot] + t * 16), 16, 0, 0);
        __builtin_amdgcn_global_load_lds(AS1C(vg + (kt << 6)),
                                         AS3(sV[slot] + t * 16), 16, 0, 0);
    };

    const int swz0 = (lg ^ (lr & 7)) * 16;
    const int swz1 = ((4 + lg) ^ (lr & 7)) * 16;
    const float SC = 0.18033688f;  // 0.125 * log2(e)

    float m_run[4] = {-1e30f, -1e30f, -1e30f, -1e30f};
    float l_run[4] = {0.f, 0.f, 0.f, 0.f};
    f32x4 o[4] = {};
    unsigned short* sPw = sP[w];
    int nkv = S >> 6;

    STAGE(0);
    for (int kt = 0; kt < nkv; ++kt) {
        if (kt + 1 < nkv) {
            STAGE(kt + 1);
            asm volatile("s_waitcnt vmcnt(2)" ::: "memory");
        } else {
            asm volatile("s_waitcnt vmcnt(0)" ::: "memory");
        }
        __builtin_amdgcn_s_barrier();
        FENCE();
        const char* kb = sK[kt & 1];
        const char* vb = sV[kt & 1];
        f32x4 s[4];
#pragma unroll
        for (int n = 0; n < 4; ++n) {
            const char* kr = kb + (n * 16 + lr) * 128;
            b16x8 bk0 = *(const b16x8*)(kr + swz0);
            b16x8 bk1 = *(const b16x8*)(kr + swz1);
            f32x4 z = {};
            z = __builtin_amdgcn_mfma_f32_16x16x32_bf16(aq0, bk0, z, 0, 0, 0);
            z = __builtin_amdgcn_mfma_f32_16x16x32_bf16(aq1, bk1, z, 0, 0, 0);
            s[n] = z * SC;
        }
        float p[4][4];
#pragma unroll
        for (int r = 0; r < 4; ++r) {
            float tm = fmaxf(fmaxf(s[0][r], s[1][r]), fmaxf(s[2][r], s[3][r]));
            tm = fmaxf(tm, __shfl_xor(tm, 1));
            tm = fmaxf(tm, __shfl_xor(tm, 2));
            tm = fmaxf(tm, __shfl_xor(tm, 4));
            tm = fmaxf(tm, __shfl_xor(tm, 8));
            float mn = fmaxf(m_run[r], tm);
            float alpha = exp2_f(m_run[r] - mn);
            m_run[r] = mn;
            float rs = 0.f;
#pragma unroll
            for (int n = 0; n < 4; ++n) {
                float pv = exp2_f(s[n][r] - mn);
                p[n][r] = pv;
                rs += pv;
            }
            rs += __shfl_xor(rs, 1);
            rs += __shfl_xor(rs, 2);
            rs += __shfl_xor(rs, 4);
            rs += __shfl_xor(rs, 8);
            l_run[r] = l_run[r] * alpha + rs;
#pragma unroll
            for (int n = 0; n < 4; ++n) o[n][r] *= alpha;
        }
#pragma unroll
        for (int r = 0; r < 4; ++r)
#pragma unroll
            for (int n = 0; n < 4; ++n)
                sPw[(lg * 4 + r) * 72 + n * 16 + lr] = f2bf(p[n][r]);
        b16x8 ap0 = *(const b16x8*)(&sPw[lr * 72 + lg * 8]);
        b16x8 ap1 = *(const b16x8*)(&sPw[lr * 72 + 32 + lg * 8]);
#pragma unroll
        for (int n = 0; n < 4; ++n) {
            const char* vr = vb + (n * 16 + lr) * 128;
            b16x8 bv0 = *(const b16x8*)(vr + swz0);
            b16x8 bv1 = *(const b16x8*)(vr + swz1);
            o[n] = __builtin_amdgcn_mfma_f32_16x16x32_bf16(ap0, bv0, o[n], 0, 0, 0);
            o[n] = __builtin_amdgcn_mfma_f32_16x16x32_bf16(ap1, bv1, o[n], 0, 0, 0);
        }
        FENCE();
        if (kt + 1 < nkv) __builtin_amdgcn_s_barrier();
        FENCE();
    }
#pragma unroll
    for (int r = 0; r < 4; ++r) {
        float inv = 1.0f / l_run[r];
#pragma unroll
        for (int n = 0; n < 4; ++n)
            aout[(size_t)(tok0 + w * 16 + lg * 4 + r) * 1024 + hoff + n * 16 + lr] =
                f2bf(o[n][r] * inv);
    }
}

// ---------------------------------------------------------------------------
// Launch
// ---------------------------------------------------------------------------
extern "C" void kernel_launch(void* const* d_in, const int* in_sizes, int n_in,
                              void* d_out, int out_size, void* d_ws, size_t ws_size,
                              hipStream_t stream) {
    const float* x1     = (const float*)d_in[0];
    const float* x2     = (const float*)d_in[1];
    const float* w_qkv  = (const float*)d_in[2];
    const float* b_qkv  = (const float*)d_in[3];
    const float* w_proj = (const float*)d_in[4];
    const float* b_proj = (const float*)d_in[5];
    const float* ln1w   = (const float*)d_in[6];
    const float* ln1b   = (const float*)d_in[7];
    const float* ln2w   = (const float*)d_in[8];
    const float* ln2b   = (const float*)d_in[9];
    const float* w_fc1  = (const float*)d_in[10];
    const float* b_fc1  = (const float*)d_in[11];
    const float* w_fc2  = (const float*)d_in[12];
    const float* b_fc2  = (const float*)d_in[13];
    const float* gamma1 = (const float*)d_in[14];
    const float* gamma2 = (const float*)d_in[15];
    float* out = (float*)d_out;
    char* ws = (char*)d_ws;

    // Workspace layout (144 MiB total)
    unsigned short* wqkvT  = (unsigned short*)(ws);              //  6291456 B
    unsigned short* wprojT = (unsigned short*)(ws + 6291456);    //  2097152 B
    unsigned short* wfc1T  = (unsigned short*)(ws + 8388608);    //  8388608 B
    unsigned short* wfc2T  = (unsigned short*)(ws + 16777216);   //  8388608 B
    unsigned short* lnbuf  = (unsigned short*)(ws + 25165824);   // 25165824 B (also vT later)
    unsigned short* qkvbuf = (unsigned short*)(ws + 50331648);   // 75497472 B
    unsigned short* attnbuf= (unsigned short*)(ws + 125829120);  // 25165824 B
    unsigned short* actbuf = (unsigned short*)(ws + 50331648);   // aliases qkv+attn (dead by then)
    unsigned short* vTbuf  = lnbuf;                              // 1024 x 12288 bf16

    // 1) weights -> bf16, transposed to [N][K]
    wtrans_k<<<dim3(96, 32), 256, 0, stream>>>(w_qkv, wqkvT, 1024, 3072);
    wtrans_k<<<dim3(32, 32), 256, 0, stream>>>(w_proj, wprojT, 1024, 1024);
    wtrans_k<<<dim3(128, 32), 256, 0, stream>>>(w_fc1, wfc1T, 1024, 4096);
    wtrans_k<<<dim3(32, 128), 256, 0, stream>>>(w_fc2, wfc2T, 4096, 1024);
    // 2) LN1 over packed tokens
    ln_k<<<12288, 256, 0, stream>>>(x1, x2, 8192, ln1w, ln1b, lnbuf);
    // 3) qkv = LN1(x) @ w_qkv + b_qkv          [12288,3072] bf16
    gemm3_k<1024, 3072, 0><<<576, 512, 0, stream>>>(lnbuf, wqkvT, b_qkv, nullptr, nullptr,
                                                    nullptr, nullptr, qkvbuf);
    // 3b) vT[c][tok] = V part of qkv
    vtrans_k<<<dim3(384, 32), 256, 0, stream>>>(qkvbuf, vTbuf);
    // 4) flash attention -> attnbuf [12288,1024] bf16
    attn_k<<<1536, 512, 0, stream>>>(qkvbuf, vTbuf, attnbuf);
    // 5) y = x + gamma1*(attn @ w_proj + b_proj)  -> d_out f32
    gemm3_k<1024, 1024, 1><<<192, 512, 0, stream>>>(attnbuf, wprojT, b_proj, gamma1, x1, x2,
                                                    out, nullptr);
    // 6) LN2 over y
    ln_k<<<12288, 256, 0, stream>>>(out, out + (size_t)8192 * 1024, 8192, ln2w, ln2b, lnbuf);
    // 7) act = gelu(LN2 @ w_fc1 + b_fc1)        [12288,4096] bf16
    gemm3_k<1024, 4096, 2><<<768, 512, 0, stream>>>(lnbuf, wfc1T, b_fc1, nullptr, nullptr,
                                                    nullptr, nullptr, actbuf);
    // 8) out += gamma2*(act @ w_fc2 + b_fc2)
    gemm3_k<4096, 1024, 3><<<192, 512, 0, stream>>>(actbuf, wfc2T, b_fc2, gamma2, nullptr,
                                                    nullptr, out, nullptr);
}